// Round 10
// baseline (274.266 us; speedup 1.0000x reference)
//
#include <hip/hip_runtime.h>
#include <hip/hip_bf16.h>

#define BATCH 2
#define SEQ   2048
#define DIM   1024
#define HEADS 16
#define DIMH  64
#define LOG2E 1.44269504088896340736f
#define SM_SHIFT 16.0f   // fixed softmax shift (log2 domain); |st| <= ~12

typedef __attribute__((ext_vector_type(8))) short short8;
typedef __attribute__((ext_vector_type(4))) short short4v;
typedef __attribute__((ext_vector_type(4))) float floatx4;

static __device__ __forceinline__ void gload_lds16(const void* g, void* l) {
    __builtin_amdgcn_global_load_lds(
        (const __attribute__((address_space(1))) void*)g,
        (__attribute__((address_space(3))) void*)l, 16, 0, 0);
}

// truncation pack: bf16(a) | bf16(b)<<16 (scale-invariant err cancels in P*V/sum)
static __device__ __forceinline__ unsigned pk_trunc(float a, float b) {
    return (__float_as_uint(b) & 0xffff0000u) | (__float_as_uint(a) >> 16);
}

// ---------------------------------------------------------------------------
// One conversion pass: x,Wq,Wk,Wv -> d_out scratch [0,4M|4M..7M); Wo -> dwo.
// ---------------------------------------------------------------------------
__global__ __launch_bounds__(256) void conv_all(
    const float* __restrict__ x,  const float* __restrict__ Wq,
    const float* __restrict__ Wk, const float* __restrict__ Wv,
    const float* __restrict__ Wo,
    __hip_bfloat16* __restrict__ dst, __hip_bfloat16* __restrict__ dwo)
{
    const size_t NX = (size_t)BATCH * SEQ * DIM;   // 4M
    const size_t NW = (size_t)DIM * DIM;           // 1M
    size_t i = ((size_t)blockIdx.x * 256 + threadIdx.x) * 4;
    if (i >= NX + 4 * NW) return;
    const float* src; __hip_bfloat16* d;
    if (i < NX) { src = x + i; d = dst + i; }
    else if (i < NX + 3 * NW) {
        size_t j = i - NX;
        int w = (int)(j >> 20);
        src = ((w == 0) ? Wq : (w == 1) ? Wk : Wv) + (j & (NW - 1));
        d = dst + i;
    } else {
        size_t off = i - (NX + 3 * NW);
        src = Wo + off; d = dwo + off;
    }
    floatx4 f = *reinterpret_cast<const floatx4*>(src);
    short4v o;
    #pragma unroll
    for (int e = 0; e < 4; ++e) {
        __hip_bfloat16 t = __float2bfloat16(f[e]);
        o[e] = *reinterpret_cast<short*>(&t);
    }
    *reinterpret_cast<short4v*>(d) = o;
}

// ---------------------------------------------------------------------------
// Merged QKV GEMM, BK=64, XOR-swizzled chunks.  z = n0>>10.
// z==0: Q pre-scaled by 0.125*log2e, head-split; z==1: K head-split;
// z==2: V transposed [b,h,dv,n].
// ---------------------------------------------------------------------------
__global__ __launch_bounds__(256) void gemm_qkv(
    const __hip_bfloat16* __restrict__ xbf,
    const __hip_bfloat16* __restrict__ wbf,
    __hip_bfloat16* __restrict__ qkv)
{
    __shared__ __align__(16) short As[128 * 64];
    __shared__ __align__(16) short Bs[128 * 64];

    const int tid  = threadIdx.x;
    const int wv   = tid >> 6;
    const int lane = tid & 63;
    const int quad = lane >> 4;
    const int l16  = lane & 15;
    const int xr   = l16 & 7;
    const int wm   = wv >> 1, wn = wv & 1;
    const int m0   = blockIdx.x * 128;
    const int n0   = blockIdx.y * 128;
    const int z    = n0 >> 10;
    __hip_bfloat16* out = qkv + (size_t)z * (BATCH * SEQ * DIM);

    const int srow = tid >> 3;
    const int sjc  = tid & 7;

    floatx4 acc[4][4] = {};

    for (int k0 = 0; k0 < DIM; k0 += 64) {
        __syncthreads();
        #pragma unroll
        for (int i = 0; i < 4; ++i) {
            const int row = srow + i * 32;
            const int sg  = sjc ^ (row & 7);
            gload_lds16(xbf + (size_t)(m0 + row) * DIM + k0 + sg * 8,
                        (char*)As + i * 4096 + wv * 1024);
            gload_lds16(wbf + (size_t)(n0 + row) * DIM + k0 + sg * 8,
                        (char*)Bs + i * 4096 + wv * 1024);
        }
        __syncthreads();

        short8 af[2][4], bf_[2][4];
        #pragma unroll
        for (int kk = 0; kk < 2; ++kk) {
            #pragma unroll
            for (int mt = 0; mt < 4; ++mt)
                af[kk][mt] = *reinterpret_cast<const short8*>(
                    &As[(wm * 64 + mt * 16 + l16) * 64 + ((kk * 4 + quad) ^ xr) * 8]);
            #pragma unroll
            for (int nt = 0; nt < 4; ++nt)
                bf_[kk][nt] = *reinterpret_cast<const short8*>(
                    &Bs[(wn * 64 + nt * 16 + l16) * 64 + ((kk * 4 + quad) ^ xr) * 8]);
        }
        #pragma unroll
        for (int kk = 0; kk < 2; ++kk)
            #pragma unroll
            for (int mt = 0; mt < 4; ++mt)
                #pragma unroll
                for (int nt = 0; nt < 4; ++nt)
                    acc[mt][nt] = __builtin_amdgcn_mfma_f32_16x16x32_bf16(
                        af[kk][mt], bf_[kk][nt], acc[mt][nt], 0, 0, 0);
    }

    const float esc = (z == 0) ? (0.125f * LOG2E) : 1.0f;
    #pragma unroll
    for (int mt = 0; mt < 4; ++mt) {
        #pragma unroll
        for (int nt = 0; nt < 4; ++nt) {
            const int n  = n0 + wn * 64 + nt * 16 + l16;
            const int hh = (n >> 6) & 15, dv = n & 63;
            #pragma unroll
            for (int r = 0; r < 4; ++r) {
                const int m  = m0 + wm * 64 + mt * 16 + quad * 4 + r;
                const int bb = m >> 11, nn = m & (SEQ - 1);
                const float v = acc[mt][nt][r] * esc;
                if (z < 2)
                    out[((size_t)(bb * HEADS + hh) * SEQ + nn) * DIMH + dv] = __float2bfloat16(v);
                else
                    out[((size_t)(bb * HEADS + hh) * DIMH + dv) * SEQ + nn] = __float2bfloat16(v);
            }
        }
    }
}

// ---------------------------------------------------------------------------
// Output projection, 128x128 tile, BK=64 swizzled.  A read from head-split
// Q region (attn wrote O in-place): token m, feature k ->
// qhs[((b*H + k>>6)*SEQ + n)*64 + (k&63)].
// ---------------------------------------------------------------------------
__global__ __launch_bounds__(256) void gemm_out(
    const __hip_bfloat16* __restrict__ qhs,
    const __hip_bfloat16* __restrict__ W,
    float* __restrict__ C)
{
    __shared__ __align__(16) short As[128 * 64];
    __shared__ __align__(16) short Bs[128 * 64];

    const int tid  = threadIdx.x;
    const int wv   = tid >> 6;
    const int lane = tid & 63;
    const int quad = lane >> 4;
    const int l16  = lane & 15;
    const int xr   = l16 & 7;
    const int wm   = wv >> 1, wn = wv & 1;
    const int m0   = blockIdx.x * 128;
    const int n0   = blockIdx.y * 128;

    const int srow = tid >> 3;
    const int sjc  = tid & 7;

    floatx4 acc[4][4] = {};

    for (int k0 = 0; k0 < DIM; k0 += 64) {
        const int h = k0 >> 6;     // one head per k-step
        __syncthreads();
        #pragma unroll
        for (int i = 0; i < 4; ++i) {
            const int row = srow + i * 32;
            const int sg  = sjc ^ (row & 7);
            const int m   = m0 + row;
            const int bb  = m >> 11, nn = m & (SEQ - 1);
            gload_lds16(qhs + ((size_t)(bb * HEADS + h) * SEQ + nn) * DIMH + sg * 8,
                        (char*)As + i * 4096 + wv * 1024);
            gload_lds16(W + (size_t)(n0 + row) * DIM + k0 + sg * 8,
                        (char*)Bs + i * 4096 + wv * 1024);
        }
        __syncthreads();

        short8 af[2][4], bf_[2][4];
        #pragma unroll
        for (int kk = 0; kk < 2; ++kk) {
            #pragma unroll
            for (int mt = 0; mt < 4; ++mt)
                af[kk][mt] = *reinterpret_cast<const short8*>(
                    &As[(wm * 64 + mt * 16 + l16) * 64 + ((kk * 4 + quad) ^ xr) * 8]);
            #pragma unroll
            for (int nt = 0; nt < 4; ++nt)
                bf_[kk][nt] = *reinterpret_cast<const short8*>(
                    &Bs[(wn * 64 + nt * 16 + l16) * 64 + ((kk * 4 + quad) ^ xr) * 8]);
        }
        #pragma unroll
        for (int kk = 0; kk < 2; ++kk)
            #pragma unroll
            for (int mt = 0; mt < 4; ++mt)
                #pragma unroll
                for (int nt = 0; nt < 4; ++nt)
                    acc[mt][nt] = __builtin_amdgcn_mfma_f32_16x16x32_bf16(
                        af[kk][mt], bf_[kk][nt], acc[mt][nt], 0, 0, 0);
    }

    #pragma unroll
    for (int mt = 0; mt < 4; ++mt)
        #pragma unroll
        for (int nt = 0; nt < 4; ++nt) {
            const int n = n0 + wn * 64 + nt * 16 + l16;
            #pragma unroll
            for (int r = 0; r < 4; ++r) {
                const int m = m0 + wm * 64 + mt * 16 + quad * 4 + r;
                C[(size_t)m * DIM + n] = acc[mt][nt][r];
            }
        }
}

// ---------------------------------------------------------------------------
// Causal flash attention v7: ONE WAVE PER BLOCK (16-q tile), paired tiles
// p & 127-p -> uniform 33 steps, NO __syncthreads, NO K/V LDS.
// K/V fragments load directly global->VGPR (L2-resident; XCD-pinned grid).
// K prefetched one step ahead in registers; V issued at step start and
// consumed after softmax.  LDS only for the wave-private P^T round-trip.
// Fixed-shift softmax; O written in-place over Q (head-split).
// ---------------------------------------------------------------------------
__global__ __launch_bounds__(64) void attn_causal(
    __hip_bfloat16* __restrict__ qkv)
{
    __shared__ __align__(16) short pt[16 * 72];   // 2304 B, wave-private

    const int id    = blockIdx.x;        // 0..2047
    const int combo = id & 31;           // (h,b): combo%8 pins XCD class
    const int p     = id >> 5;           // pair index 0..63 over 16-q tiles
    const int b     = combo >> 4;
    const int h     = combo & 15;
    const int tA = p, tB = 127 - p;
    const int nA = (tA >> 2) + 1;        // steps for tile t = t/4 + 1
    const int nB = (tB >> 2) + 1;
    const int total = nA + nB;           // 33 for all blocks

    const size_t hoff = (size_t)(b * HEADS + h) * SEQ * DIMH;
    const size_t one  = (size_t)BATCH * SEQ * DIM;
    __hip_bfloat16* qb        = qkv + hoff;             // Q in, O out (in-place)
    const __hip_bfloat16* kb  = qkv + one + hoff;       // [n][dv]
    const __hip_bfloat16* vtg = qkv + 2 * one + hoff;   // [dv][n]

    const int lane = threadIdx.x & 63;
    const int quad = lane >> 4;
    const int l16  = lane & 15;

    const short8 kone8 = {0x3F80, 0x3F80, 0x3F80, 0x3F80,
                          0x3F80, 0x3F80, 0x3F80, 0x3F80};

    int q16 = tA * 16;
    short8 aq0 = *reinterpret_cast<const short8*>(qb + (size_t)(q16 + l16) * DIMH + quad * 8);
    short8 aq1 = *reinterpret_cast<const short8*>(qb + (size_t)(q16 + l16) * DIMH + 32 + quad * 8);
    floatx4 oacc[4] = {};
    floatx4 lsum = {};

    // prefetch K(j0=0) fragments: A-operand rows t*16+l16, chunks quad / quad+4
    short8 kf[4][2];
    #pragma unroll
    for (int t = 0; t < 4; ++t) {
        const __hip_bfloat16* kr = kb + (size_t)(t * 16 + l16) * DIMH + quad * 8;
        kf[t][0] = *reinterpret_cast<const short8*>(kr);
        kf[t][1] = *reinterpret_cast<const short8*>(kr + 32);
    }

    for (int s = 0; s < total; ++s) {
        const bool lastA = (s == nA - 1);
        const int j0 = ((s < nA) ? s : s - nA) * 64;

        // issue V loads for this step (consumed after softmax)
        short8 vf[4][2];
        #pragma unroll
        for (int dt = 0; dt < 4; ++dt) {
            const __hip_bfloat16* vr = vtg + (size_t)(dt * 16 + l16) * SEQ + j0 + quad * 8;
            vf[dt][0] = *reinterpret_cast<const short8*>(vr);
            vf[dt][1] = *reinterpret_cast<const short8*>(vr + 32);
        }

        // St[j][q] = K Q^T from prefetched K frags
        floatx4 st[4];
        #pragma unroll
        for (int t = 0; t < 4; ++t) {
            floatx4 zz = {};
            zz    = __builtin_amdgcn_mfma_f32_16x16x32_bf16(kf[t][0], aq0, zz, 0, 0, 0);
            st[t] = __builtin_amdgcn_mfma_f32_16x16x32_bf16(kf[t][1], aq1, zz, 0, 0, 0);
        }

        // prefetch next step's K (flies across softmax + PV)
        if (s + 1 < total) {
            const int s2 = s + 1;
            const int j1 = ((s2 < nA) ? s2 : s2 - nA) * 64;
            #pragma unroll
            for (int t = 0; t < 4; ++t) {
                const __hip_bfloat16* kr = kb + (size_t)(j1 + t * 16 + l16) * DIMH + quad * 8;
                kf[t][0] = *reinterpret_cast<const short8*>(kr);
                kf[t][1] = *reinterpret_cast<const short8*>(kr + 32);
            }
        }

        if (j0 + 63 > q16) {             // diagonal step
            const int qg = q16 + l16;
            #pragma unroll
            for (int t = 0; t < 4; ++t)
                #pragma unroll
                for (int r = 0; r < 4; ++r) {
                    const int jg = j0 + t * 16 + quad * 4 + r;
                    if (jg > qg) st[t][r] = -3.0e38f;
                }
        }

        #pragma unroll
        for (int t = 0; t < 4; ++t)
            #pragma unroll
            for (int r = 0; r < 4; ++r)
                st[t][r] = __builtin_amdgcn_exp2f(st[t][r] - SM_SHIFT);

        // P^T via wave-private LDS round-trip: pt[q=l16][j]
        #pragma unroll
        for (int t = 0; t < 4; ++t) {
            *reinterpret_cast<unsigned*>(&pt[l16 * 72 + t * 16 + quad * 4]) =
                pk_trunc(st[t][0], st[t][1]);
            *reinterpret_cast<unsigned*>(&pt[l16 * 72 + t * 16 + quad * 4 + 2]) =
                pk_trunc(st[t][2], st[t][3]);
        }
        short8 p0 = *reinterpret_cast<const short8*>(&pt[l16 * 72 + quad * 8]);
        short8 p1 = *reinterpret_cast<const short8*>(&pt[l16 * 72 + 32 + quad * 8]);

        lsum = __builtin_amdgcn_mfma_f32_16x16x32_bf16(kone8, p0, lsum, 0, 0, 0);
        lsum = __builtin_amdgcn_mfma_f32_16x16x32_bf16(kone8, p1, lsum, 0, 0, 0);

        // O^T[dv][q] += V^T[dv][j] P^T[j][q]
        #pragma unroll
        for (int dt = 0; dt < 4; ++dt) {
            oacc[dt] = __builtin_amdgcn_mfma_f32_16x16x32_bf16(vf[dt][0], p0, oacc[dt], 0, 0, 0);
            oacc[dt] = __builtin_amdgcn_mfma_f32_16x16x32_bf16(vf[dt][1], p1, oacc[dt], 0, 0, 0);
        }

        if (lastA || s == total - 1) {   // tile finished: epilogue (+switch)
            const float rl = 1.0f / lsum[0];
            #pragma unroll
            for (int dt = 0; dt < 4; ++dt)
                #pragma unroll
                for (int r = 0; r < 4; ++r)
                    qb[(size_t)(q16 + l16) * DIMH + dt * 16 + quad * 4 + r] =
                        __float2bfloat16(oacc[dt][r] * rl);
            if (lastA) {
                q16 = tB * 16;
                aq0 = *reinterpret_cast<const short8*>(qb + (size_t)(q16 + l16) * DIMH + quad * 8);
                aq1 = *reinterpret_cast<const short8*>(qb + (size_t)(q16 + l16) * DIMH + 32 + quad * 8);
                #pragma unroll
                for (int dt = 0; dt < 4; ++dt)
                    #pragma unroll
                    for (int r = 0; r < 4; ++r) oacc[dt][r] = 0.f;
                #pragma unroll
                for (int r = 0; r < 4; ++r) lsum[r] = 0.f;
            }
        }
    }
}

// ---------------------------------------------------------------------------

extern "C" void kernel_launch(void* const* d_in, const int* in_sizes, int n_in,
                              void* d_out, int out_size, void* d_ws, size_t ws_size,
                              hipStream_t stream) {
    const float* x  = (const float*)d_in[0];
    const float* Wq = (const float*)d_in[1];
    const float* Wk = (const float*)d_in[2];
    const float* Wv = (const float*)d_in[3];
    const float* Wo = (const float*)d_in[4];

    // ws: qkv bf16 [0,24M) | wobf bf16 [24M,26M)
    __hip_bfloat16* qkv  = (__hip_bfloat16*)d_ws;
    __hip_bfloat16* wobf = (__hip_bfloat16*)((char*)d_ws + (size_t)24 * 1024 * 1024);

    // d_out (16 MB) as bf16 scratch until gemm_out overwrites it
    __hip_bfloat16* xbf = (__hip_bfloat16*)d_out;
    __hip_bfloat16* wbf = xbf + (size_t)BATCH * SEQ * DIM;

    conv_all  <<<8192, 256, 0, stream>>>(x, Wq, Wk, Wv, Wo, xbf, wobf);
    gemm_qkv  <<<dim3((BATCH * SEQ) / 128, (3 * DIM) / 128), 256, 0, stream>>>(xbf, wbf, qkv);
    attn_causal<<<dim3(2048), 64, 0, stream>>>(qkv);
    gemm_out  <<<dim3((BATCH * SEQ) / 128, DIM / 128), 256, 0, stream>>>(qkv, wobf, (float*)d_out);
}

// Round 11
// 191.959 us; speedup vs baseline: 1.4288x; 1.4288x over previous
//
#include <hip/hip_runtime.h>
#include <hip/hip_bf16.h>

#define BATCH 2
#define SEQ   2048
#define DIM   1024
#define HEADS 16
#define DIMH  64
#define BK    32
#define LOG2E 1.44269504088896340736f
#define SM_SHIFT 16.0f   // fixed softmax shift (log2 domain); |st| <= ~12

typedef __attribute__((ext_vector_type(8))) short short8;
typedef __attribute__((ext_vector_type(4))) short short4v;
typedef __attribute__((ext_vector_type(4))) float floatx4;

static __device__ __forceinline__ void gload_lds16(const void* g, void* l) {
    __builtin_amdgcn_global_load_lds(
        (const __attribute__((address_space(1))) void*)g,
        (__attribute__((address_space(3))) void*)l, 16, 0, 0);
}

// truncation pack: bf16(a) | bf16(b)<<16 (scale-invariant err cancels in P*V/sum)
static __device__ __forceinline__ unsigned pk_trunc(float a, float b) {
    return (__float_as_uint(b) & 0xffff0000u) | (__float_as_uint(a) >> 16);
}

// ---------------------------------------------------------------------------
// One conversion pass: x,Wq,Wk,Wv -> d_out scratch [0,4M | 4M..7M); Wo -> dwo.
// ---------------------------------------------------------------------------
__global__ __launch_bounds__(256) void conv_all(
    const float* __restrict__ x,  const float* __restrict__ Wq,
    const float* __restrict__ Wk, const float* __restrict__ Wv,
    const float* __restrict__ Wo,
    __hip_bfloat16* __restrict__ dst, __hip_bfloat16* __restrict__ dwo)
{
    const size_t NX = (size_t)BATCH * SEQ * DIM;   // 4M
    const size_t NW = (size_t)DIM * DIM;           // 1M
    size_t i = ((size_t)blockIdx.x * 256 + threadIdx.x) * 4;
    if (i >= NX + 4 * NW) return;
    const float* src; __hip_bfloat16* d;
    if (i < NX) { src = x + i; d = dst + i; }
    else if (i < NX + 3 * NW) {
        size_t j = i - NX;
        int w = (int)(j >> 20);
        src = ((w == 0) ? Wq : (w == 1) ? Wk : Wv) + (j & (NW - 1));
        d = dst + i;
    } else {
        size_t off = i - (NX + 3 * NW);
        src = Wo + off; d = dwo + off;
    }
    floatx4 f = *reinterpret_cast<const floatx4*>(src);
    short4v o;
    #pragma unroll
    for (int e = 0; e < 4; ++e) {
        __hip_bfloat16 t = __float2bfloat16(f[e]);
        o[e] = *reinterpret_cast<short*>(&t);
    }
    *reinterpret_cast<short4v*>(d) = o;
}

// ---------------------------------------------------------------------------
// Merged QKV GEMM, m97 structure (BK=32).  z = n0>>10.
// z==0: Q pre-scaled by 0.125*log2e, head-split; z==1: K head-split;
// z==2: V transposed [b,h,dv,n].
// ---------------------------------------------------------------------------
__global__ __launch_bounds__(256) void gemm_qkv(
    const __hip_bfloat16* __restrict__ xbf,
    const __hip_bfloat16* __restrict__ wbf,
    __hip_bfloat16* __restrict__ qkv)
{
    __shared__ __align__(16) short As[128 * BK];
    __shared__ __align__(16) short Bs[128 * BK];

    const int tid  = threadIdx.x;
    const int wv   = tid >> 6;
    const int lane = tid & 63;
    const int quad = lane >> 4;
    const int l16  = lane & 15;
    const int wm   = wv >> 1, wn = wv & 1;
    const int m0   = blockIdx.x * 128;
    const int n0   = blockIdx.y * 128;
    const int z    = n0 >> 10;
    __hip_bfloat16* out = qkv + (size_t)z * (BATCH * SEQ * DIM);

    const int srow = tid >> 2;
    const int scol = (tid & 3) * 8;

    floatx4 acc[4][4] = {};

    for (int k0 = 0; k0 < DIM; k0 += BK) {
        __syncthreads();
        #pragma unroll
        for (int i = 0; i < 2; ++i) {
            const __hip_bfloat16* ga = xbf + (size_t)(m0 + srow + i * 64) * DIM + k0 + scol;
            const __hip_bfloat16* gb = wbf + (size_t)(n0 + srow + i * 64) * DIM + k0 + scol;
            gload_lds16(ga, (char*)As + i * 4096 + wv * 1024);
            gload_lds16(gb, (char*)Bs + i * 4096 + wv * 1024);
        }
        __syncthreads();

        short8 af[4], bf[4];
        #pragma unroll
        for (int mt = 0; mt < 4; ++mt)
            af[mt] = *reinterpret_cast<const short8*>(&As[(wm * 64 + mt * 16 + l16) * 32 + quad * 8]);
        #pragma unroll
        for (int nt = 0; nt < 4; ++nt)
            bf[nt] = *reinterpret_cast<const short8*>(&Bs[(wn * 64 + nt * 16 + l16) * 32 + quad * 8]);
        #pragma unroll
        for (int mt = 0; mt < 4; ++mt)
            #pragma unroll
            for (int nt = 0; nt < 4; ++nt)
                acc[mt][nt] = __builtin_amdgcn_mfma_f32_16x16x32_bf16(
                    af[mt], bf[nt], acc[mt][nt], 0, 0, 0);
    }

    const float esc = (z == 0) ? (0.125f * LOG2E) : 1.0f;
    #pragma unroll
    for (int mt = 0; mt < 4; ++mt) {
        #pragma unroll
        for (int nt = 0; nt < 4; ++nt) {
            const int n  = n0 + wn * 64 + nt * 16 + l16;
            const int hh = (n >> 6) & 15, dv = n & 63;
            #pragma unroll
            for (int r = 0; r < 4; ++r) {
                const int m  = m0 + wm * 64 + mt * 16 + quad * 4 + r;
                const int bb = m >> 11, nn = m & (SEQ - 1);
                const float v = acc[mt][nt][r] * esc;
                if (z < 2)
                    out[((size_t)(bb * HEADS + hh) * SEQ + nn) * DIMH + dv] = __float2bfloat16(v);
                else
                    out[((size_t)(bb * HEADS + hh) * DIMH + dv) * SEQ + nn] = __float2bfloat16(v);
            }
        }
    }
}

// ---------------------------------------------------------------------------
// Output projection, m97 structure (BK=32), A gathered from head-split Q
// region (attn wrote O in-place).  k-step covers half a head: h = k0>>6,
// koff = k0 & 63 (block-uniform).
// ---------------------------------------------------------------------------
__global__ __launch_bounds__(256) void gemm_out(
    const __hip_bfloat16* __restrict__ qhs,
    const __hip_bfloat16* __restrict__ W,
    float* __restrict__ C)
{
    __shared__ __align__(16) short As[128 * BK];
    __shared__ __align__(16) short Bs[128 * BK];

    const int tid  = threadIdx.x;
    const int wv   = tid >> 6;
    const int lane = tid & 63;
    const int quad = lane >> 4;
    const int l16  = lane & 15;
    const int wm   = wv >> 1, wn = wv & 1;
    const int m0   = blockIdx.x * 128;
    const int n0   = blockIdx.y * 128;

    const int srow = tid >> 2;
    const int scol = (tid & 3) * 8;

    floatx4 acc[4][4] = {};

    for (int k0 = 0; k0 < DIM; k0 += BK) {
        const int h    = k0 >> 6;
        const int koff = k0 & 63;
        __syncthreads();
        #pragma unroll
        for (int i = 0; i < 2; ++i) {
            const int m  = m0 + srow + i * 64;
            const int bb = m >> 11, nn = m & (SEQ - 1);
            gload_lds16(qhs + ((size_t)(bb * HEADS + h) * SEQ + nn) * DIMH + koff + scol,
                        (char*)As + i * 4096 + wv * 1024);
            gload_lds16(W + (size_t)(n0 + srow + i * 64) * DIM + k0 + scol,
                        (char*)Bs + i * 4096 + wv * 1024);
        }
        __syncthreads();

        short8 af[4], bf[4];
        #pragma unroll
        for (int mt = 0; mt < 4; ++mt)
            af[mt] = *reinterpret_cast<const short8*>(&As[(wm * 64 + mt * 16 + l16) * 32 + quad * 8]);
        #pragma unroll
        for (int nt = 0; nt < 4; ++nt)
            bf[nt] = *reinterpret_cast<const short8*>(&Bs[(wn * 64 + nt * 16 + l16) * 32 + quad * 8]);
        #pragma unroll
        for (int mt = 0; mt < 4; ++mt)
            #pragma unroll
            for (int nt = 0; nt < 4; ++nt)
                acc[mt][nt] = __builtin_amdgcn_mfma_f32_16x16x32_bf16(
                    af[mt], bf[nt], acc[mt][nt], 0, 0, 0);
    }

    #pragma unroll
    for (int mt = 0; mt < 4; ++mt)
        #pragma unroll
        for (int nt = 0; nt < 4; ++nt) {
            const int n = n0 + wn * 64 + nt * 16 + l16;
            #pragma unroll
            for (int r = 0; r < 4; ++r) {
                const int m = m0 + wm * 64 + mt * 16 + quad * 4 + r;
                C[(size_t)m * DIM + n] = acc[mt][nt][r];
            }
        }
}

// ---------------------------------------------------------------------------
// Causal flash attention (round-8 structure, best measured: 56.6 us):
// paired 32-q tiles (uniform 33 steps/block), 128-thread blocks, register-
// staged K/V -> LDS commit, fixed-shift softmax, XCD-pinned grid.
// O written in-place over Q (block-private rows).
// ---------------------------------------------------------------------------
__global__ __launch_bounds__(128) void attn_causal(
    __hip_bfloat16* __restrict__ qkv)
{
    __shared__ __align__(16) short kt[64 * 64];     // [j][k], swizzled chunks
    __shared__ __align__(16) short vt[64 * 64];     // [dv][j], swizzled chunks
    __shared__ __align__(16) short pt[2][16 * 72];  // per-wave P^T [q][j]

    const int id    = blockIdx.x;        // 0..1023
    const int combo = id & 31;           // (h,b): combo%8 pins XCD class
    const int p     = id >> 5;           // pair index 0..31
    const int b     = combo >> 4;
    const int h     = combo & 15;
    const int tA = p, tB = 63 - p;
    const int nA = (tA + 2) >> 1;
    const int nB = (tB + 2) >> 1;
    const int total = nA + nB;           // 33 for all blocks

    const size_t hoff = (size_t)(b * HEADS + h) * SEQ * DIMH;
    const size_t one  = (size_t)BATCH * SEQ * DIM;
    __hip_bfloat16* qb        = qkv + hoff;             // Q in, O out (in-place)
    const __hip_bfloat16* kb  = qkv + one + hoff;       // [n][dv]
    const __hip_bfloat16* vtg = qkv + 2 * one + hoff;   // [dv][n]

    const int tid  = threadIdx.x;
    const int wv   = tid >> 6;
    const int lane = tid & 63;
    const int quad = lane >> 4;
    const int l16  = lane & 15;
    const int xr   = l16 & 7;

    const short8 kone8 = {0x3F80, 0x3F80, 0x3F80, 0x3F80,
                          0x3F80, 0x3F80, 0x3F80, 0x3F80};

    int q16 = tA * 32 + wv * 16;
    short8 aq0 = *reinterpret_cast<const short8*>(qb + (size_t)(q16 + l16) * DIMH + quad * 8);
    short8 aq1 = *reinterpret_cast<const short8*>(qb + (size_t)(q16 + l16) * DIMH + 32 + quad * 8);
    floatx4 oacc[4] = {};
    floatx4 lsum = {};

    short8 kreg[4], vreg[4];
    #pragma unroll
    for (int i = 0; i < 4; ++i) {        // preload j0 = 0
        const int c = tid + 128 * i;
        const int row = c >> 3, jc = c & 7;
        kreg[i] = *reinterpret_cast<const short8*>(kb + (size_t)row * DIMH + jc * 8);
        vreg[i] = *reinterpret_cast<const short8*>(vtg + (size_t)row * SEQ + jc * 8);
    }

    for (int s = 0; s < total; ++s) {
        const bool lastA = (s == nA - 1);
        const int j0 = ((s < nA) ? s : s - nA) * 64;

        __syncthreads();
        #pragma unroll
        for (int i = 0; i < 4; ++i) {
            const int c = tid + 128 * i;
            const int row = c >> 3, jc = c & 7;
            const int off = row * 64 + ((jc ^ (row & 7)) * 8);
            *reinterpret_cast<short8*>(&kt[off]) = kreg[i];
            *reinterpret_cast<short8*>(&vt[off]) = vreg[i];
        }
        __syncthreads();

        if (s + 1 < total) {             // prefetch next step's K/V into regs
            const int s2 = s + 1;
            const int j1 = ((s2 < nA) ? s2 : s2 - nA) * 64;
            #pragma unroll
            for (int i = 0; i < 4; ++i) {
                const int c = tid + 128 * i;
                const int row = c >> 3, jc = c & 7;
                kreg[i] = *reinterpret_cast<const short8*>(kb + (size_t)(j1 + row) * DIMH + jc * 8);
                vreg[i] = *reinterpret_cast<const short8*>(vtg + (size_t)row * SEQ + j1 + jc * 8);
            }
        }

        // St[j][q] = K Q^T
        floatx4 st[4];
        #pragma unroll
        for (int t = 0; t < 4; ++t) {
            const int rw = t * 16 + l16;
            short8 a0 = *reinterpret_cast<const short8*>(&kt[rw * 64 + (quad ^ xr) * 8]);
            short8 a1 = *reinterpret_cast<const short8*>(&kt[rw * 64 + ((quad + 4) ^ xr) * 8]);
            floatx4 zz = {};
            zz    = __builtin_amdgcn_mfma_f32_16x16x32_bf16(a0, aq0, zz, 0, 0, 0);
            st[t] = __builtin_amdgcn_mfma_f32_16x16x32_bf16(a1, aq1, zz, 0, 0, 0);
        }

        if (j0 + 63 > q16) {             // diagonal step for this wave
            const int qg = q16 + l16;
            #pragma unroll
            for (int t = 0; t < 4; ++t)
                #pragma unroll
                for (int r = 0; r < 4; ++r) {
                    const int jg = j0 + t * 16 + quad * 4 + r;
                    if (jg > qg) st[t][r] = -3.0e38f;
                }
        }

        #pragma unroll
        for (int t = 0; t < 4; ++t)
            #pragma unroll
            for (int r = 0; r < 4; ++r)
                st[t][r] = __builtin_amdgcn_exp2f(st[t][r] - SM_SHIFT);

        // P^T pack (b32 pairs): pt[q=l16][j]
        #pragma unroll
        for (int t = 0; t < 4; ++t) {
            *reinterpret_cast<unsigned*>(&pt[wv][l16 * 72 + t * 16 + quad * 4]) =
                pk_trunc(st[t][0], st[t][1]);
            *reinterpret_cast<unsigned*>(&pt[wv][l16 * 72 + t * 16 + quad * 4 + 2]) =
                pk_trunc(st[t][2], st[t][3]);
        }
        short8 p0 = *reinterpret_cast<const short8*>(&pt[wv][l16 * 72 + quad * 8]);
        short8 p1 = *reinterpret_cast<const short8*>(&pt[wv][l16 * 72 + 32 + quad * 8]);

        lsum = __builtin_amdgcn_mfma_f32_16x16x32_bf16(kone8, p0, lsum, 0, 0, 0);
        lsum = __builtin_amdgcn_mfma_f32_16x16x32_bf16(kone8, p1, lsum, 0, 0, 0);

        // O^T[dv][q] += V^T[dv][j] P^T[j][q]
        #pragma unroll
        for (int dt = 0; dt < 4; ++dt) {
            const int rw = dt * 16 + l16;
            short8 v0 = *reinterpret_cast<const short8*>(&vt[rw * 64 + (quad ^ xr) * 8]);
            short8 v1 = *reinterpret_cast<const short8*>(&vt[rw * 64 + ((quad + 4) ^ xr) * 8]);
            oacc[dt] = __builtin_amdgcn_mfma_f32_16x16x32_bf16(v0, p0, oacc[dt], 0, 0, 0);
            oacc[dt] = __builtin_amdgcn_mfma_f32_16x16x32_bf16(v1, p1, oacc[dt], 0, 0, 0);
        }

        if (lastA || s == total - 1) {   // tile finished: epilogue (+switch)
            const float rl = 1.0f / lsum[0];
            #pragma unroll
            for (int dt = 0; dt < 4; ++dt)
                #pragma unroll
                for (int r = 0; r < 4; ++r)
                    qb[(size_t)(q16 + l16) * DIMH + dt * 16 + quad * 4 + r] =
                        __float2bfloat16(oacc[dt][r] * rl);
            if (lastA) {
                q16 = tB * 32 + wv * 16;
                aq0 = *reinterpret_cast<const short8*>(qb + (size_t)(q16 + l16) * DIMH + quad * 8);
                aq1 = *reinterpret_cast<const short8*>(qb + (size_t)(q16 + l16) * DIMH + 32 + quad * 8);
                #pragma unroll
                for (int dt = 0; dt < 4; ++dt)
                    #pragma unroll
                    for (int r = 0; r < 4; ++r) oacc[dt][r] = 0.f;
                #pragma unroll
                for (int r = 0; r < 4; ++r) lsum[r] = 0.f;
            }
        }
    }
}

// ---------------------------------------------------------------------------

extern "C" void kernel_launch(void* const* d_in, const int* in_sizes, int n_in,
                              void* d_out, int out_size, void* d_ws, size_t ws_size,
                              hipStream_t stream) {
    const float* x  = (const float*)d_in[0];
    const float* Wq = (const float*)d_in[1];
    const float* Wk = (const float*)d_in[2];
    const float* Wv = (const float*)d_in[3];
    const float* Wo = (const float*)d_in[4];

    // ws: qkv bf16 [0,24M) | wobf bf16 [24M,26M)
    __hip_bfloat16* qkv  = (__hip_bfloat16*)d_ws;
    __hip_bfloat16* wobf = (__hip_bfloat16*)((char*)d_ws + (size_t)24 * 1024 * 1024);

    // d_out (16 MB) as bf16 scratch until gemm_out overwrites it
    __hip_bfloat16* xbf = (__hip_bfloat16*)d_out;
    __hip_bfloat16* wbf = xbf + (size_t)BATCH * SEQ * DIM;

    conv_all  <<<8192, 256, 0, stream>>>(x, Wq, Wk, Wv, Wo, xbf, wobf);
    gemm_qkv  <<<dim3((BATCH * SEQ) / 128, (3 * DIM) / 128), 256, 0, stream>>>(xbf, wbf, qkv);
    attn_causal<<<dim3(1024), 128, 0, stream>>>(qkv);
    gemm_out  <<<dim3((BATCH * SEQ) / 128, DIM / 128), 256, 0, stream>>>(qkv, wobf, (float*)d_out);
}